// Round 3
// 354.802 us; speedup vs baseline: 1.0718x; 1.0718x over previous
//
#include <hip/hip_runtime.h>

// ---------------------------------------------------------------------------
// CormorantCGProduct on MI355X — round 1 kernel, resubmit #2 (rounds 1-2 were
// infra failures: GPU acquisition timeout, then container failure; no data).
// Inputs (setup_inputs dict order — INTERLEAVED): A0,B0,A1,B1,A2,B2,A3,B3,
//   each fp32 shape (2, N, 2l+1, 16).
// Output: concat over l=0..3 of (2, N, 2l+1, CH_l), CH_l = 256*npairs_l,
//   pairs in l1-major/l2-minor order, channels c*16+d.
//
// Store-BW-bound op: 327 MB out vs 4 MB in.  This version:
//   * ONE fused product kernel for all 34 (l1,l2,L) triples
//     (blockIdx.y = triple; constexpr table -> template dispatch; no LDS,
//      no barrier, no per-block serial segment search).
//   * thread = (triple, n, c, d4); A-row/B-row register-cached ONCE and
//     reused across all z; fully unrolled compile-time (z,x) loops ->
//     pure FMA + batched loads; per thread 2*zdim contiguous float4 stores.
//   * CG coefficients computed on-device each call into d_ws
//     (graph-capture safe; d_ws is re-poisoned between runs).
// ---------------------------------------------------------------------------

__device__ inline double dfact(int n) {
    double r = 1.0;
    for (int i = 2; i <= n; ++i) r *= (double)i;
    return r;
}

// Clebsch-Gordan <j1 m1 j2 m2 | j m>, Condon-Shortley, exactly as reference.
__device__ double cg_coef(int j1, int m1, int j2, int m2, int j, int m) {
    if (m1 + m2 != m) return 0.0;
    double pref = sqrt((double)(2 * j + 1)
        * dfact(j + j1 - j2) * dfact(j - j1 + j2) * dfact(j1 + j2 - j)
        / dfact(j1 + j2 + j + 1)
        * dfact(j + m) * dfact(j - m) * dfact(j1 - m1) * dfact(j1 + m1)
        * dfact(j2 - m2) * dfact(j2 + m2));
    int kmin = 0;
    if (j2 - j - m1 > kmin) kmin = j2 - j - m1;
    if (j1 - j + m2 > kmin) kmin = j1 - j + m2;
    int kmax = j1 + j2 - j;
    if (j1 - m1 < kmax) kmax = j1 - m1;
    if (j2 + m2 < kmax) kmax = j2 + m2;
    double s = 0.0;
    for (int k = kmin; k <= kmax; ++k) {
        double d = dfact(k) * dfact(j1 + j2 - j - k) * dfact(j1 - m1 - k)
                 * dfact(j2 + m2 - k) * dfact(j - j2 + m1 + k)
                 * dfact(j - j1 - m2 + k);
        s += (k & 1) ? (-1.0 / d) : (1.0 / d);
    }
    return pref * s;
}

// Writes all dense CG matrices, triple-loop order (l1, l2, l), into cgbuf.
// Total entries: 3436 floats (~13.7 KB).
__global__ void cg_init_kernel(float* __restrict__ cgbuf) {
    int tid = blockIdx.x * blockDim.x + threadIdx.x;
    int off = 0;
    for (int l1 = 0; l1 <= 3; ++l1)
    for (int l2 = 0; l2 <= 3; ++l2) {
        int lo = (l1 > l2) ? (l1 - l2) : (l2 - l1);
        int hi = (l1 + l2 < 3) ? (l1 + l2) : 3;
        for (int l = lo; l <= hi; ++l) {
            int xd = 2 * l1 + 1, yd = 2 * l2 + 1, zd = 2 * l + 1;
            int sz = xd * yd * zd;
            if (tid >= off && tid < off + sz) {
                int e = tid - off;
                int z = e % zd;
                int xy = e / zd;
                int y = xy % yd;
                int x = xy / yd;
                int m1 = x - l1, m2 = y - l2, m = z - l;
                double val = 0.0;
                if (m1 + m2 == m) val = cg_coef(l1, m1, l2, m2, l, m);
                cgbuf[tid] = (float)val;
            }
            off += sz;
        }
    }
}

// ---------------------------------------------------------------------------
// Compile-time triple table: 34 (l1,l2,L) triples in reference loop order.
// ---------------------------------------------------------------------------
struct TriTab {
    int l1[34], l2[34], L[34], c0[34], cg[34];
    int ch[4];
    long cum[4];
};

constexpr TriTab make_tab() {
    TriTab t{};
    int idx = 0, cg = 0;
    int c0L[4] = {0, 0, 0, 0};
    for (int a = 0; a <= 3; ++a)
    for (int b = 0; b <= 3; ++b) {
        int lo = (a > b) ? (a - b) : (b - a);
        int hi = (a + b < 3) ? (a + b) : 3;
        for (int l = lo; l <= hi; ++l) {
            t.l1[idx] = a; t.l2[idx] = b; t.L[idx] = l;
            t.c0[idx] = c0L[l]; c0L[l] += 256;
            t.cg[idx] = cg; cg += (2 * a + 1) * (2 * b + 1) * (2 * l + 1);
            ++idx;
        }
    }
    for (int l = 0; l < 4; ++l) t.ch[l] = c0L[l];
    long acc = 0;
    for (int l = 0; l < 4; ++l) { t.cum[l] = acc; acc += 2L * (2 * l + 1) * c0L[l]; }
    return t;
}

constexpr TriTab TAB = make_tab();

// ---------------------------------------------------------------------------
// One thread handles (triple, n, c, d4) for ALL z:
//   loads A-row (xdim scalars, re+im) and B-row (ydim float4, re+im) into
//   registers once, then for each z accumulates over the compile-time x
//   range and stores 2 float4s (re/im planes).  Per wave each store is a
//   contiguous, 64B-aligned 1KB chunk.
// ---------------------------------------------------------------------------
template <int l1, int l2, int L, int c0, int cgoff>
__device__ __forceinline__ void tri_body(
    const float* __restrict__ A0, const float* __restrict__ A1,
    const float* __restrict__ A2, const float* __restrict__ A3,
    const float* __restrict__ B0, const float* __restrict__ B1,
    const float* __restrict__ B2, const float* __restrict__ B3,
    const float* __restrict__ cgbuf, float* __restrict__ out, int N)
{
    constexpr int xdim = 2 * l1 + 1, ydim = 2 * l2 + 1, zdim = 2 * L + 1;
    constexpr int CHL = TAB.ch[L];

    const int q   = blockIdx.x * 256 + threadIdx.x;   // [0, N*64)
    const int n   = q >> 6;
    const int cd4 = q & 63;                           // wave-contiguous channels
    const int c   = cd4 >> 2;                         // tau1
    const int d4  = (cd4 & 3) << 2;                   // tau2 float4 start

    const float* Ab = (l1 == 0) ? A0 : (l1 == 1) ? A1 : (l1 == 2) ? A2 : A3;
    const float* Bb = (l2 == 0) ? B0 : (l2 == 1) ? B1 : (l2 == 2) ? B2 : B3;

    const float* Ar = Ab + (long)n * (xdim * 16) + c;
    const float* Ai = Ar + (long)N * (xdim * 16);
    const float* Br = Bb + (long)n * (ydim * 16) + d4;
    const float* Bi = Br + (long)N * (ydim * 16);
    const float* CG = cgbuf + cgoff;

    // Register-cache the A and B rows (compile-time indices only — no scratch).
    float ar[xdim], ai[xdim];
    #pragma unroll
    for (int x = 0; x < xdim; ++x) { ar[x] = Ar[x * 16]; ai[x] = Ai[x * 16]; }
    float4 br[ydim], bi[ydim];
    #pragma unroll
    for (int y = 0; y < ydim; ++y) {
        br[y] = *reinterpret_cast<const float4*>(Br + y * 16);
        bi[y] = *reinterpret_cast<const float4*>(Bi + y * 16);
    }

    long off = (long)N * TAB.cum[L] + (long)n * (zdim * CHL) + (c0 + cd4 * 4);
    const long imagOff = (long)N * (zdim * CHL);

    #pragma unroll
    for (int z = 0; z < zdim; ++z) {
        const int s   = z + l1 + l2 - L;               // folds per unrolled z
        const int xlo = (s - (ydim - 1) > 0) ? s - (ydim - 1) : 0;
        const int xhi = (s < xdim - 1) ? s : xdim - 1;
        float4 accr = make_float4(0.f, 0.f, 0.f, 0.f);
        float4 acci = make_float4(0.f, 0.f, 0.f, 0.f);
        #pragma unroll
        for (int x = xlo; x <= xhi; ++x) {
            const int y = s - x;
            const float  cgv = CG[(x * ydim + y) * zdim + z];  // uniform addr
            const float  car = cgv * ar[x];
            const float  cai = cgv * ai[x];
            const float4 brv = br[y];
            const float4 biv = bi[y];
            accr.x += car * brv.x - cai * biv.x;
            accr.y += car * brv.y - cai * biv.y;
            accr.z += car * brv.z - cai * biv.z;
            accr.w += car * brv.w - cai * biv.w;
            acci.x += car * biv.x + cai * brv.x;
            acci.y += car * biv.y + cai * brv.y;
            acci.z += car * biv.z + cai * brv.z;
            acci.w += car * biv.w + cai * brv.w;
        }
        *reinterpret_cast<float4*>(out + off) = accr;
        *reinterpret_cast<float4*>(out + off + imagOff) = acci;
        off += CHL;
    }
}

// Fused kernel: blockIdx.y = triple index (all segments within a triple have
// identical size N*64 threads -> no search).  Wave-uniform jump table.
__global__ __launch_bounds__(256) void cg_prod_all(
    const float* __restrict__ A0, const float* __restrict__ A1,
    const float* __restrict__ A2, const float* __restrict__ A3,
    const float* __restrict__ B0, const float* __restrict__ B1,
    const float* __restrict__ B2, const float* __restrict__ B3,
    const float* __restrict__ cgbuf, float* __restrict__ out, int N)
{
    switch (blockIdx.y) {
#define TC(i) case i: tri_body<TAB.l1[i], TAB.l2[i], TAB.L[i], TAB.c0[i], TAB.cg[i]>( \
        A0, A1, A2, A3, B0, B1, B2, B3, cgbuf, out, N); break;
        TC(0)  TC(1)  TC(2)  TC(3)  TC(4)  TC(5)  TC(6)  TC(7)
        TC(8)  TC(9)  TC(10) TC(11) TC(12) TC(13) TC(14) TC(15)
        TC(16) TC(17) TC(18) TC(19) TC(20) TC(21) TC(22) TC(23)
        TC(24) TC(25) TC(26) TC(27) TC(28) TC(29) TC(30) TC(31)
        TC(32) TC(33)
#undef TC
    }
}

extern "C" void kernel_launch(void* const* d_in, const int* in_sizes, int n_in,
                              void* d_out, int out_size, void* d_ws, size_t ws_size,
                              hipStream_t stream) {
    // setup_inputs() dict order is INTERLEAVED: A0,B0,A1,B1,A2,B2,A3,B3
    const float* A0 = (const float*)d_in[0];
    const float* B0 = (const float*)d_in[1];
    const float* A1 = (const float*)d_in[2];
    const float* B1 = (const float*)d_in[3];
    const float* A2 = (const float*)d_in[4];
    const float* B2 = (const float*)d_in[5];
    const float* A3 = (const float*)d_in[6];
    const float* B3 = (const float*)d_in[7];
    float* out   = (float*)d_out;
    float* cgbuf = (float*)d_ws;

    const int N = in_sizes[0] / 32;  // A0 is (2, N, 1, 16)

    // CG table must be rebuilt every call (d_ws re-poisoned before each run).
    hipLaunchKernelGGL(cg_init_kernel, dim3(14), dim3(256), 0, stream, cgbuf);

    // One fused kernel: grid.x covers N*64 threads per triple, grid.y = 34 triples.
    hipLaunchKernelGGL(cg_prod_all, dim3(N / 4, 34), dim3(256), 0, stream,
                       A0, A1, A2, A3, B0, B1, B2, B3, cgbuf, out, N);
}

// Round 11
// 344.647 us; speedup vs baseline: 1.1034x; 1.0295x over previous
//
#include <hip/hip_runtime.h>

// ---------------------------------------------------------------------------
// CormorantCGProduct on MI355X — round 4 kernel, resubmit #7 (rounds 4-10 all
// GPU-acquisition timeouts; this version has never reached hardware).
// Inputs (setup_inputs dict order — INTERLEAVED): A0,B0,A1,B1,A2,B2,A3,B3,
//   each fp32 shape (2, N, 2l+1, 16).
// Output: concat over l=0..3 of (2, N, 2l+1, CH_l), CH_l = 256*npairs_l,
//   pairs in l1-major/l2-minor order, channels c*16+d.
//
// Changes vs round 3 (354.8 µs measured; top-5 all ~222 µs poison fills):
//   * CG table is COMPILE-TIME (constexpr factorial + Newton sqrt,
//     per-triple constexpr arrays).  With fully unrolled (z,x) loops every
//     CG access folds to an immediate literal in the FMA — no cg_init
//     kernel, no d_ws, no CG loads, no second launch, parity-zero
//     coefficients dead-code-eliminated.
//   * Output written with nontemporal stores (write-once data; don't
//     stream 327 MB through L2).
//   * 32-bit offset arithmetic (total output 81.8M floats < 2^31).
// ---------------------------------------------------------------------------

typedef float f32x4 __attribute__((ext_vector_type(4)));

// ---- compile-time Clebsch-Gordan --------------------------------------
constexpr double dfactc(int n) {
    double r = 1.0;
    for (int i = 2; i <= n; ++i) r *= (double)i;
    return r;
}

// Newton-iteration sqrt; 50 iterations converge to <=1 ulp for the dynamic
// range of CG prefactors.
constexpr double csqrt(double x) {
    if (x <= 0.0) return 0.0;
    double g = x >= 1.0 ? x : 1.0;
    for (int i = 0; i < 50; ++i) g = 0.5 * (g + x / g);
    return g;
}

// <j1 m1 j2 m2 | j m>, Condon-Shortley, same formula as reference (f64).
constexpr double cg_coef_c(int j1, int m1, int j2, int m2, int j, int m) {
    if (m1 + m2 != m) return 0.0;
    double pref = csqrt((double)(2 * j + 1)
        * dfactc(j + j1 - j2) * dfactc(j - j1 + j2) * dfactc(j1 + j2 - j)
        / dfactc(j1 + j2 + j + 1)
        * dfactc(j + m) * dfactc(j - m) * dfactc(j1 - m1) * dfactc(j1 + m1)
        * dfactc(j2 - m2) * dfactc(j2 + m2));
    int kmin = 0;
    if (j2 - j - m1 > kmin) kmin = j2 - j - m1;
    if (j1 - j + m2 > kmin) kmin = j1 - j + m2;
    int kmax = j1 + j2 - j;
    if (j1 - m1 < kmax) kmax = j1 - m1;
    if (j2 + m2 < kmax) kmax = j2 + m2;
    double s = 0.0;
    for (int k = kmin; k <= kmax; ++k) {
        double d = dfactc(k) * dfactc(j1 + j2 - j - k) * dfactc(j1 - m1 - k)
                 * dfactc(j2 + m2 - k) * dfactc(j - j2 + m1 + k)
                 * dfactc(j - j1 - m2 + k);
        s += (k & 1) ? (-1.0 / d) : (1.0 / d);
    }
    return pref * s;
}

// Per-triple constexpr CG matrix (separate constexpr evaluation per triple
// keeps each initializer well under clang's constexpr-step limit).
template <int l1, int l2, int L>
struct CGMat {
    float v[(2 * l1 + 1) * (2 * l2 + 1) * (2 * L + 1)];
};

template <int l1, int l2, int L>
constexpr CGMat<l1, l2, L> make_cgmat() {
    CGMat<l1, l2, L> t{};
    constexpr int yd = 2 * l2 + 1, zd = 2 * L + 1;
    for (int x = 0; x < 2 * l1 + 1; ++x)
        for (int y = 0; y < yd; ++y)
            for (int z = 0; z < zd; ++z)
                t.v[(x * yd + y) * zd + z] =
                    (float)cg_coef_c(l1, x - l1, l2, y - l2, L, z - L);
    return t;
}

template <int l1, int l2, int L>
constexpr CGMat<l1, l2, L> CGM = make_cgmat<l1, l2, L>();

// ---------------------------------------------------------------------------
// Compile-time triple table: 34 (l1,l2,L) triples in reference loop order.
// ---------------------------------------------------------------------------
struct TriTab {
    int l1[34], l2[34], L[34], c0[34];
    int ch[4];   // channels per output degree
    int cum[4];  // output floats per unit N preceding degree L's block
};

constexpr TriTab make_tab() {
    TriTab t{};
    int idx = 0;
    int c0L[4] = {0, 0, 0, 0};
    for (int a = 0; a <= 3; ++a)
    for (int b = 0; b <= 3; ++b) {
        int lo = (a > b) ? (a - b) : (b - a);
        int hi = (a + b < 3) ? (a + b) : 3;
        for (int l = lo; l <= hi; ++l) {
            t.l1[idx] = a; t.l2[idx] = b; t.L[idx] = l;
            t.c0[idx] = c0L[l]; c0L[l] += 256;
            ++idx;
        }
    }
    for (int l = 0; l < 4; ++l) t.ch[l] = c0L[l];
    int acc = 0;
    for (int l = 0; l < 4; ++l) { t.cum[l] = acc; acc += 2 * (2 * l + 1) * c0L[l]; }
    return t;
}

constexpr TriTab TAB = make_tab();

// ---------------------------------------------------------------------------
// One thread handles (triple, n, c, d4) for ALL z:
//   A-row (xdim scalars, re+im) and B-row (ydim f32x4, re+im) register-cached
//   once; fully unrolled (z,x) loops with CG folded to literals; 2*zdim
//   nontemporal f32x4 stores (contiguous 1KB per wave per plane).
// ---------------------------------------------------------------------------
template <int l1, int l2, int L, int c0>
__device__ __forceinline__ void tri_body(
    const float* __restrict__ A0, const float* __restrict__ A1,
    const float* __restrict__ A2, const float* __restrict__ A3,
    const float* __restrict__ B0, const float* __restrict__ B1,
    const float* __restrict__ B2, const float* __restrict__ B3,
    float* __restrict__ out, int N)
{
    constexpr int xdim = 2 * l1 + 1, ydim = 2 * l2 + 1, zdim = 2 * L + 1;
    constexpr int CHL = TAB.ch[L];

    const unsigned q   = blockIdx.x * 256 + threadIdx.x;  // [0, N*64)
    const unsigned n   = q >> 6;
    const unsigned cd4 = q & 63;                          // wave-contiguous
    const unsigned c   = cd4 >> 2;                        // tau1
    const unsigned d4  = (cd4 & 3) << 2;                  // tau2 float4 start

    const float* Ab = (l1 == 0) ? A0 : (l1 == 1) ? A1 : (l1 == 2) ? A2 : A3;
    const float* Bb = (l2 == 0) ? B0 : (l2 == 1) ? B1 : (l2 == 2) ? B2 : B3;

    const float* Ar = Ab + n * (unsigned)(xdim * 16) + c;
    const float* Ai = Ar + (unsigned)N * (unsigned)(xdim * 16);
    const float* Br = Bb + n * (unsigned)(ydim * 16) + d4;
    const float* Bi = Br + (unsigned)N * (unsigned)(ydim * 16);

    // Register-cache the A and B rows (compile-time indices only).
    float ar[xdim], ai[xdim];
    #pragma unroll
    for (int x = 0; x < xdim; ++x) { ar[x] = Ar[x * 16]; ai[x] = Ai[x * 16]; }
    f32x4 br[ydim], bi[ydim];
    #pragma unroll
    for (int y = 0; y < ydim; ++y) {
        br[y] = *reinterpret_cast<const f32x4*>(Br + y * 16);
        bi[y] = *reinterpret_cast<const f32x4*>(Bi + y * 16);
    }

    unsigned off = (unsigned)N * (unsigned)TAB.cum[L]
                 + n * (unsigned)(zdim * CHL) + (unsigned)(c0) + cd4 * 4u;
    const unsigned imagOff = (unsigned)N * (unsigned)(zdim * CHL);

    #pragma unroll
    for (int z = 0; z < zdim; ++z) {
        const int s   = z + l1 + l2 - L;             // constant per unrolled z
        const int xlo = (s - (ydim - 1) > 0) ? s - (ydim - 1) : 0;
        const int xhi = (s < xdim - 1) ? s : xdim - 1;
        f32x4 accr = {0.f, 0.f, 0.f, 0.f};
        f32x4 acci = {0.f, 0.f, 0.f, 0.f};
        #pragma unroll
        for (int x = xlo; x <= xhi; ++x) {
            const int y = s - x;
            const float cgv = CGM<l1, l2, L>.v[(x * ydim + y) * zdim + z];
            if (cgv != 0.0f) {                       // folds: DCEs parity zeros
                const float car = cgv * ar[x];
                const float cai = cgv * ai[x];
                accr += car * br[y] - cai * bi[y];
                acci += car * bi[y] + cai * br[y];
            }
        }
        __builtin_nontemporal_store(accr, reinterpret_cast<f32x4*>(out + off));
        __builtin_nontemporal_store(acci, reinterpret_cast<f32x4*>(out + off + imagOff));
        off += CHL;
    }
}

// Fused kernel: blockIdx.y = triple index (uniform jump table, no LDS,
// no barrier, no search).
__global__ __launch_bounds__(256) void cg_prod_all(
    const float* __restrict__ A0, const float* __restrict__ A1,
    const float* __restrict__ A2, const float* __restrict__ A3,
    const float* __restrict__ B0, const float* __restrict__ B1,
    const float* __restrict__ B2, const float* __restrict__ B3,
    float* __restrict__ out, int N)
{
    switch (blockIdx.y) {
#define TC(i) case i: tri_body<TAB.l1[i], TAB.l2[i], TAB.L[i], TAB.c0[i]>( \
        A0, A1, A2, A3, B0, B1, B2, B3, out, N); break;
        TC(0)  TC(1)  TC(2)  TC(3)  TC(4)  TC(5)  TC(6)  TC(7)
        TC(8)  TC(9)  TC(10) TC(11) TC(12) TC(13) TC(14) TC(15)
        TC(16) TC(17) TC(18) TC(19) TC(20) TC(21) TC(22) TC(23)
        TC(24) TC(25) TC(26) TC(27) TC(28) TC(29) TC(30) TC(31)
        TC(32) TC(33)
#undef TC
    }
}

extern "C" void kernel_launch(void* const* d_in, const int* in_sizes, int n_in,
                              void* d_out, int out_size, void* d_ws, size_t ws_size,
                              hipStream_t stream) {
    // setup_inputs() dict order is INTERLEAVED: A0,B0,A1,B1,A2,B2,A3,B3
    const float* A0 = (const float*)d_in[0];
    const float* B0 = (const float*)d_in[1];
    const float* A1 = (const float*)d_in[2];
    const float* B1 = (const float*)d_in[3];
    const float* A2 = (const float*)d_in[4];
    const float* B2 = (const float*)d_in[5];
    const float* A3 = (const float*)d_in[6];
    const float* B3 = (const float*)d_in[7];
    float* out = (float*)d_out;

    const int N = in_sizes[0] / 32;  // A0 is (2, N, 1, 16)

    // Single launch: grid.x covers N*64 threads per triple, grid.y = 34 triples.
    hipLaunchKernelGGL(cg_prod_all, dim3(N / 4, 34), dim3(256), 0, stream,
                       A0, A1, A2, A3, B0, B1, B2, B3, out, N);
}

// Round 12
// 338.732 us; speedup vs baseline: 1.1226x; 1.0175x over previous
//
#include <hip/hip_runtime.h>

// ---------------------------------------------------------------------------
// CormorantCGProduct on MI355X — round 12: SEQUENTIAL-STREAM writes.
// Inputs (INTERLEAVED): A0,B0,A1,B1,A2,B2,A3,B3, each fp32 (2, N, 2l+1, 16).
// Output: concat over L=0..3 of (2, N, 2L+1, CH_L), CH_L = 256*npairs_L.
//
// r11 measured: prod ~135 µs = 2.4 TB/s effective vs fill's 6.3 TB/s.
// Hypothesis: scattered-1KB store chunks (wave writes 1KB then jumps ~10KB;
// row segments written by far-apart blocks) are the limiter.
// This version maps global wave index W -> (L, n, z, pair) with PAIR FASTEST:
//   out_offset = baseL + W'*1KB  -> consecutive waves write consecutive 1KB,
//   i.e. one long sequential stream per (L, plane) region — memset-like.
// z is now runtime per wave -> CG comes from __constant__ tables (measured
// neutral vs literals in r11). Pair/L dispatch is wave-uniform scalar.
// ---------------------------------------------------------------------------

typedef float f32x4 __attribute__((ext_vector_type(4)));

// ---- compile-time Clebsch-Gordan (same f64 formula as reference) ------
constexpr double dfactc(int n) {
    double r = 1.0;
    for (int i = 2; i <= n; ++i) r *= (double)i;
    return r;
}

constexpr double csqrt(double x) {   // Newton; 32 iters ample for our range
    if (x <= 0.0) return 0.0;
    double g = x >= 1.0 ? x : 1.0;
    for (int i = 0; i < 32; ++i) g = 0.5 * (g + x / g);
    return g;
}

constexpr double cg_coef_c(int j1, int m1, int j2, int m2, int j, int m) {
    if (m1 + m2 != m) return 0.0;
    double pref = csqrt((double)(2 * j + 1)
        * dfactc(j + j1 - j2) * dfactc(j - j1 + j2) * dfactc(j1 + j2 - j)
        / dfactc(j1 + j2 + j + 1)
        * dfactc(j + m) * dfactc(j - m) * dfactc(j1 - m1) * dfactc(j1 + m1)
        * dfactc(j2 - m2) * dfactc(j2 + m2));
    int kmin = 0;
    if (j2 - j - m1 > kmin) kmin = j2 - j - m1;
    if (j1 - j + m2 > kmin) kmin = j1 - j + m2;
    int kmax = j1 + j2 - j;
    if (j1 - m1 < kmax) kmax = j1 - m1;
    if (j2 + m2 < kmax) kmax = j2 + m2;
    double s = 0.0;
    for (int k = kmin; k <= kmax; ++k) {
        double d = dfactc(k) * dfactc(j1 + j2 - j - k) * dfactc(j1 - m1 - k)
                 * dfactc(j2 + m2 - k) * dfactc(j - j2 + m1 + k)
                 * dfactc(j - j1 - m2 + k);
        s += (k & 1) ? (-1.0 / d) : (1.0 / d);
    }
    return pref * s;
}

// ---- per-L pair lists (l1-major, l2-minor — reference concat order) ---
struct PairList {
    int l1[11], l2[11], off[11];  // off = float offset of pair's CG block
    int np, total;
};

constexpr PairList plist(int L) {
    PairList P{};
    int np = 0, off = 0;
    for (int a = 0; a <= 3; ++a)
    for (int b = 0; b <= 3; ++b) {
        int lo = (a > b) ? (a - b) : (b - a);
        int hi = (a + b < 3) ? (a + b) : 3;
        if (lo <= L && L <= hi) {
            P.l1[np] = a; P.l2[np] = b; P.off[np] = off;
            off += (2 * a + 1) * (2 * b + 1) * (2 * L + 1);
            ++np;
        }
    }
    P.np = np; P.total = off;
    return P;
}

// npairs: L0=4, L1=9, L2=11, L3=10.  Output floats per n preceding block L:
constexpr int cum_floats(int L) {
    int acc = 0;
    for (int l = 0; l < L; ++l) acc += 2 * (2 * l + 1) * 256 * plist(l).np;
    return acc;
}

// ---- __constant__ CG tables, one per L (3436 floats total, ~13.7 KB) --
template <int L> struct CGTabT { float v[plist(L).total]; };

template <int L>
constexpr CGTabT<L> make_cgtab() {
    CGTabT<L> t{};
    constexpr PairList P = plist(L);
    constexpr int zd = 2 * L + 1;
    for (int p = 0; p < P.np; ++p) {
        const int l1 = P.l1[p], l2 = P.l2[p];
        const int yd = 2 * l2 + 1;
        for (int x = 0; x < 2 * l1 + 1; ++x)
            for (int y = 0; y < yd; ++y)
                for (int z = 0; z < zd; ++z)
                    t.v[P.off[p] + (x * yd + y) * zd + z] =
                        (float)cg_coef_c(l1, x - l1, l2, y - l2, L, z - L);
    }
    return t;
}

__constant__ CGTabT<0> CGT0 = make_cgtab<0>();
__constant__ CGTabT<1> CGT1 = make_cgtab<1>();
__constant__ CGTabT<2> CGT2 = make_cgtab<2>();
__constant__ CGTabT<3> CGT3 = make_cgtab<3>();

// ---------------------------------------------------------------------------
// One WAVE handles one (L, n, z, pair) = one 256-channel row segment:
// lane covers f32x4 at channel p*256 + lane*4  (c = lane>>2, d4 = (lane&3)*4).
// Wave's two stores (re/im) are 1KB contiguous; consecutive waves are
// address-consecutive within each (L, plane) region.
// ---------------------------------------------------------------------------
template <int l1, int l2, int L>
__device__ __forceinline__ void pair_body(
    const float* __restrict__ A0, const float* __restrict__ A1,
    const float* __restrict__ A2, const float* __restrict__ A3,
    const float* __restrict__ B0, const float* __restrict__ B1,
    const float* __restrict__ B2, const float* __restrict__ B3,
    const float* __restrict__ cg, int cgoff,
    unsigned z, unsigned n, unsigned lane,
    float* __restrict__ out, unsigned rowOff, unsigned imagOff, int N)
{
    constexpr int xdim = 2 * l1 + 1, ydim = 2 * l2 + 1, zdim = 2 * L + 1;

    const int s   = (int)z + l1 + l2 - L;
    const int xlo = (s - (ydim - 1) > 0) ? s - (ydim - 1) : 0;
    const int xhi = (s < xdim - 1) ? s : (xdim - 1);

    const unsigned c  = lane >> 2;
    const unsigned d4 = (lane & 3u) << 2;

    const float* Ab = (l1 == 0) ? A0 : (l1 == 1) ? A1 : (l1 == 2) ? A2 : A3;
    const float* Bb = (l2 == 0) ? B0 : (l2 == 1) ? B1 : (l2 == 2) ? B2 : B3;

    const float* Ar = Ab + n * (unsigned)(xdim * 16) + c;
    const float* Ai = Ar + (unsigned)N * (unsigned)(xdim * 16);
    const float* Br = Bb + n * (unsigned)(ydim * 16) + d4;
    const float* Bi = Br + (unsigned)N * (unsigned)(ydim * 16);

    // Register-cache A row (static indices); B loaded per-x from L1 (hot).
    float ar[xdim], ai[xdim];
    #pragma unroll
    for (int x = 0; x < xdim; ++x) { ar[x] = Ar[x * 16]; ai[x] = Ai[x * 16]; }

    const int cgbase = cgoff + s * zdim + (int)z;

    f32x4 accr = {0.f, 0.f, 0.f, 0.f};
    f32x4 acci = {0.f, 0.f, 0.f, 0.f};
    #pragma unroll
    for (int x = 0; x < xdim; ++x) {
        if (x >= xlo && x <= xhi) {           // wave-uniform guard
            const float cgv = cg[cgbase + x * (ydim - 1) * zdim];
            const float car = cgv * ar[x];
            const float cai = cgv * ai[x];
            const f32x4 brv = *reinterpret_cast<const f32x4*>(Br + (unsigned)(s - x) * 16u);
            const f32x4 biv = *reinterpret_cast<const f32x4*>(Bi + (unsigned)(s - x) * 16u);
            accr += car * brv - cai * biv;
            acci += car * biv + cai * brv;
        }
    }

    float* oR = out + rowOff + lane * 4u;
    __builtin_nontemporal_store(accr, reinterpret_cast<f32x4*>(oR));
    __builtin_nontemporal_store(acci, reinterpret_cast<f32x4*>(oR + imagOff));
}

template <int L>
__device__ __forceinline__ void doL(unsigned w, unsigned lane,
    const float* __restrict__ A0, const float* __restrict__ A1,
    const float* __restrict__ A2, const float* __restrict__ A3,
    const float* __restrict__ B0, const float* __restrict__ B1,
    const float* __restrict__ B2, const float* __restrict__ B3,
    float* __restrict__ out, int N)
{
    constexpr int NP  = plist(L).np;
    constexpr int ZD  = 2 * L + 1;
    constexpr int CHL = 256 * NP;

    // pair fastest -> out offset linear in w
    const unsigned p = w % (unsigned)NP;
    const unsigned r = w / (unsigned)NP;
    const unsigned z = r % (unsigned)ZD;
    const unsigned n = r / (unsigned)ZD;

    const unsigned rowOff  = (unsigned)N * (unsigned)cum_floats(L) + w * 256u;
    const unsigned imagOff = (unsigned)N * (unsigned)(ZD * CHL);

    const float* cg = (L == 0) ? CGT0.v : (L == 1) ? CGT1.v
                    : (L == 2) ? CGT2.v : CGT3.v;

#define PB(Lv, K) case K: pair_body<plist(Lv).l1[K], plist(Lv).l2[K], Lv>( \
        A0, A1, A2, A3, B0, B1, B2, B3, cg, plist(Lv).off[K], z, n, lane,  \
        out, rowOff, imagOff, N); break;

    if constexpr (L == 0) {
        switch (p) { PB(0,0) PB(0,1) PB(0,2) PB(0,3) }
    } else if constexpr (L == 1) {
        switch (p) { PB(1,0) PB(1,1) PB(1,2) PB(1,3) PB(1,4) PB(1,5) PB(1,6) PB(1,7) PB(1,8) }
    } else if constexpr (L == 2) {
        switch (p) { PB(2,0) PB(2,1) PB(2,2) PB(2,3) PB(2,4) PB(2,5) PB(2,6) PB(2,7) PB(2,8) PB(2,9) PB(2,10) }
    } else {
        switch (p) { PB(3,0) PB(3,1) PB(3,2) PB(3,3) PB(3,4) PB(3,5) PB(3,6) PB(3,7) PB(3,8) PB(3,9) }
    }
#undef PB
}

// Wave-slot counts per L (waves per unit N): L0: 1*4=4, L1: 3*9=27,
// L2: 5*11=55, L3: 7*10=70.  Cumulative: 4, 31, 86, 156.
__global__ __launch_bounds__(256) void cg_prod_seq(
    const float* __restrict__ A0, const float* __restrict__ A1,
    const float* __restrict__ A2, const float* __restrict__ A3,
    const float* __restrict__ B0, const float* __restrict__ B1,
    const float* __restrict__ B2, const float* __restrict__ B3,
    float* __restrict__ out, int N)
{
    const unsigned gtid = blockIdx.x * 256u + threadIdx.x;
    const unsigned lane = threadIdx.x & 63u;
    unsigned W = gtid >> 6;
    W = (unsigned)__builtin_amdgcn_readfirstlane((int)W);  // scalarize

    const unsigned NN = (unsigned)N;
    if (W < 4u * NN) {
        doL<0>(W,            lane, A0, A1, A2, A3, B0, B1, B2, B3, out, N);
    } else if (W < 31u * NN) {
        doL<1>(W - 4u * NN,  lane, A0, A1, A2, A3, B0, B1, B2, B3, out, N);
    } else if (W < 86u * NN) {
        doL<2>(W - 31u * NN, lane, A0, A1, A2, A3, B0, B1, B2, B3, out, N);
    } else if (W < 156u * NN) {
        doL<3>(W - 86u * NN, lane, A0, A1, A2, A3, B0, B1, B2, B3, out, N);
    }
}

extern "C" void kernel_launch(void* const* d_in, const int* in_sizes, int n_in,
                              void* d_out, int out_size, void* d_ws, size_t ws_size,
                              hipStream_t stream) {
    // setup_inputs() dict order is INTERLEAVED: A0,B0,A1,B1,A2,B2,A3,B3
    const float* A0 = (const float*)d_in[0];
    const float* B0 = (const float*)d_in[1];
    const float* A1 = (const float*)d_in[2];
    const float* B1 = (const float*)d_in[3];
    const float* A2 = (const float*)d_in[4];
    const float* B2 = (const float*)d_in[5];
    const float* A3 = (const float*)d_in[6];
    const float* B3 = (const float*)d_in[7];
    float* out = (float*)d_out;
    (void)d_ws; (void)ws_size;

    const int N = in_sizes[0] / 32;  // A0 is (2, N, 1, 16)

    // 156*N waves total, 4 waves/block -> 39*N blocks (exact for N%... 156N%4==0).
    const int blocks = (156 * N + 3) / 4 / 256 * 256 ? (39 * N) : (39 * N);
    hipLaunchKernelGGL(cg_prod_seq, dim3(39 * N), dim3(256), 0, stream,
                       A0, A1, A2, A3, B0, B1, B2, B3, out, N);
}